// Round 4
// baseline (594.493 us; speedup 1.0000x reference)
//
#include <hip/hip_runtime.h>
#include <math.h>

#define CIN 32
#define COUT 64
#define DIM 48
#define PD 24
#define D3 110592  // 48^3

// padded channels-last volume: [16][50][50][50][32] bf16
#define XP_W 50
#define XP_POS 125000           // 50^3 positions per image
#define XB_BYTES 128000000ull   // 16 * 125000 * 32 * 2

typedef __bf16 bf16x8 __attribute__((ext_vector_type(8)));
typedef float f32x4 __attribute__((ext_vector_type(4)));

__device__ __forceinline__ unsigned bf16_rne(float f) {
    unsigned u = __builtin_bit_cast(unsigned, f);
    return (u + 0x7fffu + ((u >> 16) & 1u)) >> 16;
}

// Pack weights [cout][cin][3][3][3] fp32 -> wg[tap][cout][cin] bf16
__global__ __launch_bounds__(256) void wpack_kernel(const float* __restrict__ w,
                                                    unsigned short* __restrict__ wg) {
    int i = blockIdx.x * 256 + threadIdx.x;  // 0 .. 55295
    if (i >= 27 * 64 * 32) return;
    int cin = i & 31, cout = (i >> 5) & 63, tap = i >> 11;
    float v = w[(cout * CIN + cin) * 27 + tap];
    wg[i] = (unsigned short)bf16_rne(v);
}

// Pre-pass: x fp32 NCDHW -> padded channels-last bf16 xb[n][pd][ph][pw][cin]
__global__ __launch_bounds__(256) void xpack_kernel(const float* __restrict__ x,
                                                    unsigned short* __restrict__ xb) {
    int i = blockIdx.x * 256 + threadIdx.x;   // position index 0 .. 1999999
    if (i >= 16 * XP_POS) return;
    int pw = i % 50, t = i / 50, ph = t % 50, t2 = t / 50, pd = t2 % 50, n = t2 / 50;
    uint4* dst = (uint4*)(xb + (size_t)i * 32);
    int gd = pd - 1, gh = ph - 1, gw = pw - 1;
    if ((unsigned)gd < 48u && (unsigned)gh < 48u && (unsigned)gw < 48u) {
        const float* p = x + (size_t)n * CIN * D3 + ((size_t)gd * DIM + gh) * DIM + gw;
        unsigned pk[16];
#pragma unroll
        for (int cp = 0; cp < 16; ++cp) {
            float a = p[(size_t)(2 * cp) * D3];
            float b = p[(size_t)(2 * cp + 1) * D3];
            pk[cp] = bf16_rne(a) | (bf16_rne(b) << 16);
        }
#pragma unroll
        for (int q = 0; q < 4; ++q)
            dst[q] = make_uint4(pk[4 * q], pk[4 * q + 1], pk[4 * q + 2], pk[4 * q + 3]);
    } else {
        uint4 z = make_uint4(0, 0, 0, 0);
#pragma unroll
        for (int q = 0; q < 4; ++q) dst[q] = z;
    }
}

// Implicit-GEMM conv3d (bf16 MFMA) + bias + maxpool2 + logsumexp + relu.
// Block: 256 thr (4 waves), position tile (d,h,w)=(4,4,16), all 64 couts.
// R4: staging from padded channels-last xb — pure 16B chunk copies.
__global__ __launch_bounds__(256, 3) void conv_mfma_kernel(
    const unsigned short* __restrict__ xb, const unsigned short* __restrict__ wg,
    const float* __restrict__ bias, float* __restrict__ out)
{
    // x tile [ld 6][lh 6][lw 18][cin pad 40] bf16 = 51840 B
    __shared__ __align__(16) unsigned short xs[648 * 40];

    const int tid = threadIdx.x;
    const int bw = blockIdx.x % 3;
    const int bh = (blockIdx.x / 3) % 12;
    const int bd = (blockIdx.x / 36) % 12;
    const int n  = blockIdx.x / 432;

    // tile origin in padded coords: pd0 = bd*4, ph0 = bh*4, pw0 = bw*16
    const unsigned short* xtile = xb + (size_t)n * (XP_POS * 32)
                                + (size_t)(bd * 4) * (2500 * 32)
                                + (bh * 4) * (50 * 32) + (bw * 16) * 32;

    // ---- stage 2592 16B-chunks (648 rows x 4), loads first then writes ----
    uint4 stg[11];
#pragma unroll
    for (int it = 0; it < 11; ++it) {
        int qq = tid + it * 256;
        if (qq < 2592) {
            int row = qq >> 2, c = qq & 3;
            int lw = row % 18, t = row / 18, lh = t % 6, ld = t / 6;
            stg[it] = *(const uint4*)(xtile + (size_t)ld * 80000 + lh * 1600 + lw * 32 + c * 8);
        }
    }
#pragma unroll
    for (int it = 0; it < 11; ++it) {
        int qq = tid + it * 256;
        if (qq < 2592) {
            int row = qq >> 2, c = qq & 3;
            *(uint4*)((char*)xs + row * 80 + c * 16) = stg[it];
        }
    }

    const int lane = tid & 63;
    const int wv = tid >> 6;        // dz
    const int m  = lane & 15;       // wz within M-tile / cout low bits
    const int ch = lane >> 4;       // k-chunk (A,B) / wz-group (C)

    const unsigned short* wgp = wg + m * 32 + ch * 8;

    // prefetch tap 0's B-fragments BEFORE the barrier (in flight during sync)
    bf16x8 bcur[4], bnxt[4];
#pragma unroll
    for (int nt = 0; nt < 4; ++nt)
        bcur[nt] = *(const bf16x8*)(wgp + nt * 512);

    __syncthreads();

    f32x4 acc[4][4];                // [hz][cout-tile]
#pragma unroll
    for (int i = 0; i < 4; ++i)
#pragma unroll
        for (int j = 0; j < 4; ++j)
            acc[i][j] = (f32x4)0.f;

#pragma unroll
    for (int tap = 0; tap < 27; ++tap) {
        if (tap < 26) {
#pragma unroll
            for (int nt = 0; nt < 4; ++nt)
                bnxt[nt] = *(const bf16x8*)(wgp + (tap + 1) * 2048 + nt * 512);
        }
        const int kd = tap / 9, kh = (tap / 3) % 3, kw = tap % 3;
        bf16x8 af[4];
#pragma unroll
        for (int hz = 0; hz < 4; ++hz) {
            const int row = ((wv + kd) * 6 + (hz + kh)) * 18 + (m + kw);
            af[hz] = *(const bf16x8*)(xs + row * 40 + ch * 8);
        }
#pragma unroll
        for (int hz = 0; hz < 4; ++hz)
#pragma unroll
            for (int nt = 0; nt < 4; ++nt)
                acc[hz][nt] = __builtin_amdgcn_mfma_f32_16x16x32_bf16(
                    af[hz], bcur[nt], acc[hz][nt], 0, 0, 0);
#pragma unroll
        for (int nt = 0; nt < 4; ++nt) bcur[nt] = bnxt[nt];
    }
    __syncthreads();  // done reading xs; reuse LDS

    // C/D layout: row(wz) = ch*4 + reg, col(cout) = nt*16 + m
    // ---- partial max over (hz pair, wz pair): pmax[dz 4][ph 2][pw 8][cout 64]
    float* pmax = (float*)xs;
#pragma unroll
    for (int ph = 0; ph < 2; ++ph)
#pragma unroll
        for (int b = 0; b < 2; ++b)
#pragma unroll
            for (int nt = 0; nt < 4; ++nt) {
                float v = fmaxf(
                    fmaxf(acc[2 * ph][nt][2 * b], acc[2 * ph][nt][2 * b + 1]),
                    fmaxf(acc[2 * ph + 1][nt][2 * b], acc[2 * ph + 1][nt][2 * b + 1]));
                int pw = 2 * ch + b;
                pmax[((wv * 2 + ph) * 8 + pw) * 64 + nt * 16 + m] = v;
            }
    __syncthreads();

    // ---- dz-pair max + bias -> pooled[cell 32][cout pad 65]
    float* pooled = pmax + 4096;
    for (int v = tid; v < 2048; v += 256) {
        int c = v & 63, cell = v >> 6;                 // cell = (pd*2+ph)*8+pw
        int pd = cell >> 4, ph = (cell >> 3) & 1, pw = cell & 7;
        int i1 = ((4 * pd + ph) * 8 + pw) * 64 + c;
        pooled[cell * 65 + c] = fmaxf(pmax[i1], pmax[i1 + 1024]) + bias[c];
    }
    __syncthreads();

    // ---- logsumexp over 64 ch + relu, 32 outputs/block
    if (tid < 32) {
        int pd = tid >> 4, ph = (tid >> 3) & 1, pw = tid & 7;
        float mx = -INFINITY;
        for (int c = 0; c < 64; ++c) mx = fmaxf(mx, pooled[tid * 65 + c]);
        float s = 0.f;
        for (int c = 0; c < 64; ++c) s += __expf(pooled[tid * 65 + c] - mx);
        float r = fmaxf(mx + __logf(s), 0.f);
        int od = bd * 2 + pd, oh = bh * 2 + ph, ow = bw * 8 + pw;
        out[((size_t)(n * PD + od) * PD + oh) * PD + ow] = r;
    }
}

// ---------------- R3 main kernel (mid fallback: ws fits weights only) ----------------
__global__ __launch_bounds__(256, 3) void conv_mfma_r3(
    const float* __restrict__ x, const unsigned short* __restrict__ wg,
    const float* __restrict__ bias, float* __restrict__ out)
{
    __shared__ __align__(16) unsigned short xs[648 * 40];
    const int tid = threadIdx.x;
    const int bw = blockIdx.x % 3;
    const int bh = (blockIdx.x / 3) % 12;
    const int bd = (blockIdx.x / 36) % 12;
    const int n  = blockIdx.x / 432;
    const int d0 = bd * 4 - 1, h0 = bh * 4 - 1, w0 = bw * 16 - 1;
    const float* xn = x + (size_t)n * CIN * D3;
    {
        const int cp = tid >> 4, sl = tid & 15;
        const float* xp0 = xn + (size_t)(cp * 2) * D3;
        for (int itb = 0; itb < 6; ++itb) {
            float f0[8], f1[8];
            int sv[8];
#pragma unroll
            for (int u = 0; u < 8; ++u) {
                const int s = sl + ((itb * 8 + u) << 4);
                sv[u] = s; f0[u] = 0.f; f1[u] = 0.f;
                if (s < 648) {
                    const int lw = s % 18, t = s / 18, lh = t % 6, ld = t / 6;
                    const int gd = d0 + ld, gh = h0 + lh, gw = w0 + lw;
                    if ((unsigned)gd < 48u && (unsigned)gh < 48u && (unsigned)gw < 48u) {
                        const float* p = xp0 + (gd * DIM + gh) * DIM + gw;
                        f0[u] = p[0]; f1[u] = p[D3];
                    }
                }
            }
#pragma unroll
            for (int u = 0; u < 8; ++u)
                if (sv[u] < 648)
                    ((unsigned*)xs)[sv[u] * 20 + cp] = bf16_rne(f0[u]) | (bf16_rne(f1[u]) << 16);
        }
    }
    const int lane = tid & 63;
    const int wv = tid >> 6;
    const int m  = lane & 15;
    const int ch = lane >> 4;
    const unsigned short* wgp = wg + m * 32 + ch * 8;
    bf16x8 bcur[4], bnxt[4];
#pragma unroll
    for (int nt = 0; nt < 4; ++nt) bcur[nt] = *(const bf16x8*)(wgp + nt * 512);
    __syncthreads();
    f32x4 acc[4][4];
#pragma unroll
    for (int i = 0; i < 4; ++i)
#pragma unroll
        for (int j = 0; j < 4; ++j) acc[i][j] = (f32x4)0.f;
#pragma unroll
    for (int tap = 0; tap < 27; ++tap) {
        if (tap < 26) {
#pragma unroll
            for (int nt = 0; nt < 4; ++nt)
                bnxt[nt] = *(const bf16x8*)(wgp + (tap + 1) * 2048 + nt * 512);
        }
        const int kd = tap / 9, kh = (tap / 3) % 3, kw = tap % 3;
        bf16x8 af[4];
#pragma unroll
        for (int hz = 0; hz < 4; ++hz) {
            const int row = ((wv + kd) * 6 + (hz + kh)) * 18 + (m + kw);
            af[hz] = *(const bf16x8*)(xs + row * 40 + ch * 8);
        }
#pragma unroll
        for (int hz = 0; hz < 4; ++hz)
#pragma unroll
            for (int nt = 0; nt < 4; ++nt)
                acc[hz][nt] = __builtin_amdgcn_mfma_f32_16x16x32_bf16(af[hz], bcur[nt], acc[hz][nt], 0, 0, 0);
#pragma unroll
        for (int nt = 0; nt < 4; ++nt) bcur[nt] = bnxt[nt];
    }
    __syncthreads();
    float* pmax = (float*)xs;
#pragma unroll
    for (int ph = 0; ph < 2; ++ph)
#pragma unroll
        for (int b = 0; b < 2; ++b)
#pragma unroll
            for (int nt = 0; nt < 4; ++nt) {
                float v = fmaxf(fmaxf(acc[2 * ph][nt][2 * b], acc[2 * ph][nt][2 * b + 1]),
                                fmaxf(acc[2 * ph + 1][nt][2 * b], acc[2 * ph + 1][nt][2 * b + 1]));
                int pw = 2 * ch + b;
                pmax[((wv * 2 + ph) * 8 + pw) * 64 + nt * 16 + m] = v;
            }
    __syncthreads();
    float* pooled = pmax + 4096;
    for (int v = tid; v < 2048; v += 256) {
        int c = v & 63, cell = v >> 6;
        int pd = cell >> 4, ph = (cell >> 3) & 1, pw = cell & 7;
        int i1 = ((4 * pd + ph) * 8 + pw) * 64 + c;
        pooled[cell * 65 + c] = fmaxf(pmax[i1], pmax[i1 + 1024]) + bias[c];
    }
    __syncthreads();
    if (tid < 32) {
        int pd = tid >> 4, ph = (tid >> 3) & 1, pw = tid & 7;
        float mx = -INFINITY;
        for (int c = 0; c < 64; ++c) mx = fmaxf(mx, pooled[tid * 65 + c]);
        float s = 0.f;
        for (int c = 0; c < 64; ++c) s += __expf(pooled[tid * 65 + c] - mx);
        float r = fmaxf(mx + __logf(s), 0.f);
        int od = bd * 2 + pd, oh = bh * 2 + ph, ow = bw * 8 + pw;
        out[((size_t)(n * PD + od) * PD + oh) * PD + ow] = r;
    }
}

// ---------------- last-resort fp32 fallback (no workspace) ----------------
__global__ __launch_bounds__(256) void conv_fused_fallback(
    const float* __restrict__ x, const float* __restrict__ wsrc,
    const float* __restrict__ bias, float* __restrict__ out)
{
    __shared__ float smem[CIN * 216];
    const int tid = threadIdx.x;
    const int bid = blockIdx.x;
    const int tw = bid % 12, th = (bid / 12) % 12, td = (bid / 144) % 12, n = bid / 1728;
    const int d0 = td * 4, h0 = th * 4, w0 = tw * 4;
    const float* xn = x + (size_t)n * CIN * D3;
    for (int i = tid; i < CIN * 216; i += 256) {
        int cin = i / 216, r = i % 216;
        int dz = r / 36, hz = (r / 6) % 6, wz = r % 6;
        int gd = d0 - 1 + dz, gh = h0 - 1 + hz, gw = w0 - 1 + wz;
        float v = 0.f;
        if ((unsigned)gd < 48u && (unsigned)gh < 48u && (unsigned)gw < 48u)
            v = xn[((cin * DIM + gd) * DIM + gh) * DIM + gw];
        smem[i] = v;
    }
    __syncthreads();
    const int lane = tid & 63;
    const int wv = __builtin_amdgcn_readfirstlane(tid >> 6);
    const int cout0 = wv * 16;
    const int ld = lane >> 4, lh = (lane >> 2) & 3, lw = lane & 3;
    float acc[16];
#pragma unroll
    for (int c = 0; c < 16; ++c) acc[c] = 0.f;
    for (int cin = 0; cin < CIN; ++cin) {
        const int xb2 = cin * 216 + ld * 36 + lh * 6 + lw;
#pragma unroll
        for (int kd = 0; kd < 3; ++kd)
#pragma unroll
            for (int kh = 0; kh < 3; ++kh)
#pragma unroll
                for (int kw = 0; kw < 3; ++kw) {
                    const float xv = smem[xb2 + kd * 36 + kh * 6 + kw];
                    const int tap = (kd * 3 + kh) * 3 + kw;
#pragma unroll
                    for (int c = 0; c < 16; ++c)
                        acc[c] = fmaf(xv, wsrc[((cout0 + c) * CIN + cin) * 27 + tap], acc[c]);
                }
    }
    __syncthreads();
    float* cb = smem;
#pragma unroll
    for (int c = 0; c < 16; ++c) cb[(wv * 64 + lane) * 16 + c] = acc[c];
    __syncthreads();
    float* pool = smem + 4096;
    for (int v = tid; v < 512; v += 256) {
        const int pp = v >> 6, c = v & 63;
        const int pd = pp >> 2, ph = (pp >> 1) & 1, pw = pp & 1;
        float mv = -INFINITY;
#pragma unroll
        for (int i = 0; i < 2; ++i)
#pragma unroll
            for (int j = 0; j < 2; ++j)
#pragma unroll
                for (int k = 0; k < 2; ++k) {
                    const int l = ((2 * pd + i) << 4) | ((2 * ph + j) << 2) | (2 * pw + k);
                    mv = fmaxf(mv, cb[((c >> 4) * 64 + l) * 16 + (c & 15)]);
                }
        pool[pp * 64 + c] = mv + bias[c];
    }
    __syncthreads();
    if (tid < 8) {
        float mx = -INFINITY;
        for (int c = 0; c < 64; ++c) mx = fmaxf(mx, pool[tid * 64 + c]);
        float s = 0.f;
        for (int c = 0; c < 64; ++c) s += __expf(pool[tid * 64 + c] - mx);
        float r = fmaxf(mx + logf(s), 0.f);
        const int pd = tid >> 2, ph = (tid >> 1) & 1, pw = tid & 1;
        const int dp = td * 2 + pd, hp = th * 2 + ph, wp = tw * 2 + pw;
        out[(((size_t)n * PD + dp) * PD + hp) * PD + wp] = r;
    }
}

extern "C" void kernel_launch(void* const* d_in, const int* in_sizes, int n_in,
                              void* d_out, int out_size, void* d_ws, size_t ws_size,
                              hipStream_t stream) {
    const float* x = (const float*)d_in[0];
    const float* w = (const float*)d_in[1];
    const float* b = (const float*)d_in[2];
    float* out = (float*)d_out;

    const size_t wg_bytes = (size_t)(27 * 64 * 32) * sizeof(unsigned short);  // 110592
    if (ws_size >= XB_BYTES + wg_bytes) {
        unsigned short* xbuf = (unsigned short*)d_ws;
        unsigned short* wgb  = (unsigned short*)((char*)d_ws + XB_BYTES);
        xpack_kernel<<<(16 * XP_POS + 255) / 256, 256, 0, stream>>>(x, xbuf);
        wpack_kernel<<<216, 256, 0, stream>>>(w, wgb);
        conv_mfma_kernel<<<16 * 12 * 12 * 3, 256, 0, stream>>>(xbuf, wgb, b, out);
    } else if (ws_size >= wg_bytes) {
        unsigned short* wgb = (unsigned short*)d_ws;
        wpack_kernel<<<216, 256, 0, stream>>>(w, wgb);
        conv_mfma_r3<<<16 * 12 * 12 * 3, 256, 0, stream>>>(x, wgb, b, out);
    } else {
        conv_fused_fallback<<<16 * 12 * 12 * 12, 256, 0, stream>>>(x, w, b, out);
    }
}

// Round 5
// 475.485 us; speedup vs baseline: 1.2503x; 1.2503x over previous
//
#include <hip/hip_runtime.h>
#include <math.h>

#define CIN 32
#define COUT 64
#define DIM 48
#define PD 24
#define D3 110592  // 48^3

// padded channels-last volume: [16][50][50][50][32] bf16
#define XP_POS 125000           // 50^3 positions per image
#define XB_BYTES 128000000ull   // 16 * 125000 * 32 * 2

typedef __bf16 bf16x8 __attribute__((ext_vector_type(8)));
typedef __bf16 bf16x4 __attribute__((ext_vector_type(4)));
typedef float f32x4 __attribute__((ext_vector_type(4)));

__device__ __forceinline__ unsigned bf16_rne(float f) {
    unsigned u = __builtin_bit_cast(unsigned, f);
    return (u + 0x7fffu + ((u >> 16) & 1u)) >> 16;
}

// Pack weights [cout][cin][3][3][3] fp32 -> wg[tap][cout][cin] bf16
__global__ __launch_bounds__(256) void wpack_kernel(const float* __restrict__ w,
                                                    unsigned short* __restrict__ wg) {
    int i = blockIdx.x * 256 + threadIdx.x;  // 0 .. 55295
    if (i >= 27 * 64 * 32) return;
    int cin = i & 31, cout = (i >> 5) & 63, tap = i >> 11;
    float v = w[(cout * CIN + cin) * 27 + tap];
    wg[i] = (unsigned short)bf16_rne(v);
}

// Pre-pass: x fp32 NCDHW -> padded channels-last bf16 xb[n][pd][ph][pw][cin]
__global__ __launch_bounds__(256) void xpack_kernel(const float* __restrict__ x,
                                                    unsigned short* __restrict__ xb) {
    int i = blockIdx.x * 256 + threadIdx.x;   // position index 0 .. 1999999
    if (i >= 16 * XP_POS) return;
    int pw = i % 50, t = i / 50, ph = t % 50, t2 = t / 50, pd = t2 % 50, n = t2 / 50;
    uint4* dst = (uint4*)(xb + (size_t)i * 32);
    int gd = pd - 1, gh = ph - 1, gw = pw - 1;
    if ((unsigned)gd < 48u && (unsigned)gh < 48u && (unsigned)gw < 48u) {
        const float* p = x + (size_t)n * CIN * D3 + ((size_t)gd * DIM + gh) * DIM + gw;
        unsigned pk[16];
#pragma unroll
        for (int cp = 0; cp < 16; ++cp) {
            float a = p[(size_t)(2 * cp) * D3];
            float b = p[(size_t)(2 * cp + 1) * D3];
            pk[cp] = bf16_rne(a) | (bf16_rne(b) << 16);
        }
#pragma unroll
        for (int q = 0; q < 4; ++q)
            dst[q] = make_uint4(pk[4 * q], pk[4 * q + 1], pk[4 * q + 2], pk[4 * q + 3]);
    } else {
        uint4 z = make_uint4(0, 0, 0, 0);
#pragma unroll
        for (int q = 0; q < 4; ++q) dst[q] = z;
    }
}

// Implicit-GEMM conv3d (bf16 MFMA) + bias + maxpool2 + logsumexp + relu.
// R5: block tile (d,h,w)=(8,4,16)=512 positions, 4 waves; wave wv owns
// dz in {2wv, 2wv+1} -> M=128/wave (halves B-operand L2 traffic per FLOP).
// LDS pitch 36 halves (72 B): word-stride 18 vs 32 banks -> b64 A-reads are
// minimum-window (conflict-free). 77.8 KB LDS -> 2 blocks/CU.
__global__ __launch_bounds__(256, 2) void conv_mfma_kernel(
    const unsigned short* __restrict__ xb, const unsigned short* __restrict__ wg,
    const float* __restrict__ bias, float* __restrict__ out)
{
    // x tile [ld 10][lh 6][lw 18] rows x 36-half pitch (32 data + 4 pad)
    __shared__ __align__(16) unsigned short xs[1080 * 36];  // 77760 B

    const int tid = threadIdx.x;
    const int bw = blockIdx.x % 3;
    const int bh = (blockIdx.x / 3) % 12;
    const int bd = (blockIdx.x / 36) % 6;
    const int n  = blockIdx.x / 216;

    // tile origin in padded coords: (bd*8, bh*4, bw*16)
    const unsigned short* xtile = xb + (size_t)n * (XP_POS * 32)
                                + (size_t)(bd * 8) * (2500 * 32)
                                + (bh * 4) * (50 * 32) + (bw * 16) * 32;

    // ---- stage 4320 16B chunks (1080 rows x 4): all loads, then writes ----
    uint4 stg[17];
#pragma unroll
    for (int it = 0; it < 17; ++it) {
        int q = tid + it * 256;
        if (q < 4320) {
            int row = q >> 2, c = q & 3;
            int lw = row % 18, t = row / 18, lh = t % 6, ld = t / 6;
            stg[it] = *(const uint4*)(xtile + (size_t)ld * 80000 + lh * 1600 + lw * 32 + c * 8);
        }
    }
#pragma unroll
    for (int it = 0; it < 17; ++it) {
        int q = tid + it * 256;
        if (q < 4320) {
            int row = q >> 2, c = q & 3;
            char* p = (char*)xs + row * 72 + c * 16;
            *(uint2*)p       = make_uint2(stg[it].x, stg[it].y);
            *(uint2*)(p + 8) = make_uint2(stg[it].z, stg[it].w);
        }
    }

    const int lane = tid & 63;
    const int wv = tid >> 6;        // output pd = wv; dz in {2wv, 2wv+1}
    const int m  = lane & 15;       // wz within M-tile / cout low bits
    const int ch = lane >> 4;       // k-chunk (A,B) / wz-group (C)

    const unsigned short* wgp = wg + m * 32 + ch * 8;

    float breg[4];
#pragma unroll
    for (int nt = 0; nt < 4; ++nt) breg[nt] = bias[nt * 16 + m];

    // prefetch tap 0's B-fragments BEFORE the barrier
    bf16x8 bcur[4], bnxt[4];
#pragma unroll
    for (int nt = 0; nt < 4; ++nt)
        bcur[nt] = *(const bf16x8*)(wgp + nt * 512);

    __syncthreads();

    f32x4 acc[2][4][4];             // [dz offset j][hz][cout-tile]
#pragma unroll
    for (int j = 0; j < 2; ++j)
#pragma unroll
        for (int i = 0; i < 4; ++i)
#pragma unroll
            for (int k = 0; k < 4; ++k)
                acc[j][i][k] = (f32x4)0.f;

#pragma unroll
    for (int tap = 0; tap < 27; ++tap) {
        if (tap < 26) {
#pragma unroll
            for (int nt = 0; nt < 4; ++nt)
                bnxt[nt] = *(const bf16x8*)(wgp + (tap + 1) * 2048 + nt * 512);
        }
        const int kd = tap / 9, kh = (tap / 3) % 3, kw = tap % 3;
        bf16x8 af[2][4];
#pragma unroll
        for (int j = 0; j < 2; ++j)
#pragma unroll
            for (int hz = 0; hz < 4; ++hz) {
                const int row = ((2 * wv + j + kd) * 6 + (hz + kh)) * 18 + (m + kw);
                const unsigned short* p = xs + row * 36 + ch * 8;
                bf16x4 lo = *(const bf16x4*)p;
                bf16x4 hi = *(const bf16x4*)(p + 4);
                af[j][hz] = __builtin_shufflevector(lo, hi, 0, 1, 2, 3, 4, 5, 6, 7);
            }
#pragma unroll
        for (int j = 0; j < 2; ++j)
#pragma unroll
            for (int hz = 0; hz < 4; ++hz)
#pragma unroll
                for (int nt = 0; nt < 4; ++nt)
                    acc[j][hz][nt] = __builtin_amdgcn_mfma_f32_16x16x32_bf16(
                        af[j][hz], bcur[nt], acc[j][hz][nt], 0, 0, 0);
#pragma unroll
        for (int nt = 0; nt < 4; ++nt) bcur[nt] = bnxt[nt];
    }
    __syncthreads();  // done reading xs; reuse LDS

    // C/D layout: wz = ch*4 + reg, cout = nt*16 + m
    // wave's dz pair pools to pd = wv directly -> no cross-wave d-max.
    // pooled[cell 64][cout pad 65], cell = (pd*2+ph)*8+pw
    float* pooled = (float*)xs;
#pragma unroll
    for (int ph = 0; ph < 2; ++ph)
#pragma unroll
        for (int b = 0; b < 2; ++b)
#pragma unroll
            for (int nt = 0; nt < 4; ++nt) {
                float v =          acc[0][2 * ph][nt][2 * b];
                v = fmaxf(v,       acc[0][2 * ph][nt][2 * b + 1]);
                v = fmaxf(v,       acc[0][2 * ph + 1][nt][2 * b]);
                v = fmaxf(v,       acc[0][2 * ph + 1][nt][2 * b + 1]);
                v = fmaxf(v,       acc[1][2 * ph][nt][2 * b]);
                v = fmaxf(v,       acc[1][2 * ph][nt][2 * b + 1]);
                v = fmaxf(v,       acc[1][2 * ph + 1][nt][2 * b]);
                v = fmaxf(v,       acc[1][2 * ph + 1][nt][2 * b + 1]);
                int cell = (wv * 2 + ph) * 8 + 2 * ch + b;
                pooled[cell * 65 + nt * 16 + m] = v + breg[nt];
            }
    __syncthreads();

    // ---- logsumexp over 64 ch + relu, 64 outputs per block ----
    if (tid < 64) {
        float mx = -INFINITY;
        for (int c = 0; c < 64; ++c) mx = fmaxf(mx, pooled[tid * 65 + c]);
        float s = 0.f;
        for (int c = 0; c < 64; ++c) s += __expf(pooled[tid * 65 + c] - mx);
        float r = fmaxf(mx + __logf(s), 0.f);
        int od = bd * 4 + (tid >> 4), oh = bh * 2 + ((tid >> 3) & 1), ow = bw * 8 + (tid & 7);
        out[((size_t)(n * PD + od) * PD + oh) * PD + ow] = r;
    }
}

// ---------------- R3 main kernel (mid fallback: ws fits weights only) ----------------
__global__ __launch_bounds__(256, 3) void conv_mfma_r3(
    const float* __restrict__ x, const unsigned short* __restrict__ wg,
    const float* __restrict__ bias, float* __restrict__ out)
{
    __shared__ __align__(16) unsigned short xsr[648 * 40];
    const int tid = threadIdx.x;
    const int bw = blockIdx.x % 3;
    const int bh = (blockIdx.x / 3) % 12;
    const int bd = (blockIdx.x / 36) % 12;
    const int n  = blockIdx.x / 432;
    const int d0 = bd * 4 - 1, h0 = bh * 4 - 1, w0 = bw * 16 - 1;
    const float* xn = x + (size_t)n * CIN * D3;
    {
        const int cp = tid >> 4, sl = tid & 15;
        const float* xp0 = xn + (size_t)(cp * 2) * D3;
        for (int itb = 0; itb < 6; ++itb) {
            float f0[8], f1[8];
            int sv[8];
#pragma unroll
            for (int u = 0; u < 8; ++u) {
                const int s = sl + ((itb * 8 + u) << 4);
                sv[u] = s; f0[u] = 0.f; f1[u] = 0.f;
                if (s < 648) {
                    const int lw = s % 18, t = s / 18, lh = t % 6, ld = t / 6;
                    const int gd = d0 + ld, gh = h0 + lh, gw = w0 + lw;
                    if ((unsigned)gd < 48u && (unsigned)gh < 48u && (unsigned)gw < 48u) {
                        const float* p = xp0 + (gd * DIM + gh) * DIM + gw;
                        f0[u] = p[0]; f1[u] = p[D3];
                    }
                }
            }
#pragma unroll
            for (int u = 0; u < 8; ++u)
                if (sv[u] < 648)
                    ((unsigned*)xsr)[sv[u] * 20 + cp] = bf16_rne(f0[u]) | (bf16_rne(f1[u]) << 16);
        }
    }
    const int lane = tid & 63;
    const int wv = tid >> 6;
    const int m  = lane & 15;
    const int ch = lane >> 4;
    const unsigned short* wgp = wg + m * 32 + ch * 8;
    bf16x8 bcur[4], bnxt[4];
#pragma unroll
    for (int nt = 0; nt < 4; ++nt) bcur[nt] = *(const bf16x8*)(wgp + nt * 512);
    __syncthreads();
    f32x4 acc[4][4];
#pragma unroll
    for (int i = 0; i < 4; ++i)
#pragma unroll
        for (int j = 0; j < 4; ++j) acc[i][j] = (f32x4)0.f;
#pragma unroll
    for (int tap = 0; tap < 27; ++tap) {
        if (tap < 26) {
#pragma unroll
            for (int nt = 0; nt < 4; ++nt)
                bnxt[nt] = *(const bf16x8*)(wgp + (tap + 1) * 2048 + nt * 512);
        }
        const int kd = tap / 9, kh = (tap / 3) % 3, kw = tap % 3;
        bf16x8 af[4];
#pragma unroll
        for (int hz = 0; hz < 4; ++hz) {
            const int row = ((wv + kd) * 6 + (hz + kh)) * 18 + (m + kw);
            af[hz] = *(const bf16x8*)(xsr + row * 40 + ch * 8);
        }
#pragma unroll
        for (int hz = 0; hz < 4; ++hz)
#pragma unroll
            for (int nt = 0; nt < 4; ++nt)
                acc[hz][nt] = __builtin_amdgcn_mfma_f32_16x16x32_bf16(af[hz], bcur[nt], acc[hz][nt], 0, 0, 0);
#pragma unroll
        for (int nt = 0; nt < 4; ++nt) bcur[nt] = bnxt[nt];
    }
    __syncthreads();
    float* pmax = (float*)xsr;
#pragma unroll
    for (int ph = 0; ph < 2; ++ph)
#pragma unroll
        for (int b = 0; b < 2; ++b)
#pragma unroll
            for (int nt = 0; nt < 4; ++nt) {
                float v = fmaxf(fmaxf(acc[2 * ph][nt][2 * b], acc[2 * ph][nt][2 * b + 1]),
                                fmaxf(acc[2 * ph + 1][nt][2 * b], acc[2 * ph + 1][nt][2 * b + 1]));
                int pw = 2 * ch + b;
                pmax[((wv * 2 + ph) * 8 + pw) * 64 + nt * 16 + m] = v;
            }
    __syncthreads();
    float* pooled = pmax + 4096;
    for (int v = tid; v < 2048; v += 256) {
        int c = v & 63, cell = v >> 6;
        int pd = cell >> 4, ph = (cell >> 3) & 1, pw = cell & 7;
        int i1 = ((4 * pd + ph) * 8 + pw) * 64 + c;
        pooled[cell * 65 + c] = fmaxf(pmax[i1], pmax[i1 + 1024]) + bias[c];
    }
    __syncthreads();
    if (tid < 32) {
        int pd = tid >> 4, ph = (tid >> 3) & 1, pw = tid & 7;
        float mx = -INFINITY;
        for (int c = 0; c < 64; ++c) mx = fmaxf(mx, pooled[tid * 65 + c]);
        float s = 0.f;
        for (int c = 0; c < 64; ++c) s += __expf(pooled[tid * 65 + c] - mx);
        float r = fmaxf(mx + __logf(s), 0.f);
        int od = bd * 2 + pd, oh = bh * 2 + ph, ow = bw * 8 + pw;
        out[((size_t)(n * PD + od) * PD + oh) * PD + ow] = r;
    }
}

// ---------------- last-resort fp32 fallback (no workspace) ----------------
__global__ __launch_bounds__(256) void conv_fused_fallback(
    const float* __restrict__ x, const float* __restrict__ wsrc,
    const float* __restrict__ bias, float* __restrict__ out)
{
    __shared__ float smem[CIN * 216];
    const int tid = threadIdx.x;
    const int bid = blockIdx.x;
    const int tw = bid % 12, th = (bid / 12) % 12, td = (bid / 144) % 12, n = bid / 1728;
    const int d0 = td * 4, h0 = th * 4, w0 = tw * 4;
    const float* xn = x + (size_t)n * CIN * D3;
    for (int i = tid; i < CIN * 216; i += 256) {
        int cin = i / 216, r = i % 216;
        int dz = r / 36, hz = (r / 6) % 6, wz = r % 6;
        int gd = d0 - 1 + dz, gh = h0 - 1 + hz, gw = w0 - 1 + wz;
        float v = 0.f;
        if ((unsigned)gd < 48u && (unsigned)gh < 48u && (unsigned)gw < 48u)
            v = xn[((cin * DIM + gd) * DIM + gh) * DIM + gw];
        smem[i] = v;
    }
    __syncthreads();
    const int lane = tid & 63;
    const int wv = __builtin_amdgcn_readfirstlane(tid >> 6);
    const int cout0 = wv * 16;
    const int ld = lane >> 4, lh = (lane >> 2) & 3, lw = lane & 3;
    float acc[16];
#pragma unroll
    for (int c = 0; c < 16; ++c) acc[c] = 0.f;
    for (int cin = 0; cin < CIN; ++cin) {
        const int xb2 = cin * 216 + ld * 36 + lh * 6 + lw;
#pragma unroll
        for (int kd = 0; kd < 3; ++kd)
#pragma unroll
            for (int kh = 0; kh < 3; ++kh)
#pragma unroll
                for (int kw = 0; kw < 3; ++kw) {
                    const float xv = smem[xb2 + kd * 36 + kh * 6 + kw];
                    const int tap = (kd * 3 + kh) * 3 + kw;
#pragma unroll
                    for (int c = 0; c < 16; ++c)
                        acc[c] = fmaf(xv, wsrc[((cout0 + c) * CIN + cin) * 27 + tap], acc[c]);
                }
    }
    __syncthreads();
    float* cb = smem;
#pragma unroll
    for (int c = 0; c < 16; ++c) cb[(wv * 64 + lane) * 16 + c] = acc[c];
    __syncthreads();
    float* pool = smem + 4096;
    for (int v = tid; v < 512; v += 256) {
        const int pp = v >> 6, c = v & 63;
        const int pd = pp >> 2, ph = (pp >> 1) & 1, pw = pp & 1;
        float mv = -INFINITY;
#pragma unroll
        for (int i = 0; i < 2; ++i)
#pragma unroll
            for (int j = 0; j < 2; ++j)
#pragma unroll
                for (int k = 0; k < 2; ++k) {
                    const int l = ((2 * pd + i) << 4) | ((2 * ph + j) << 2) | (2 * pw + k);
                    mv = fmaxf(mv, cb[((c >> 4) * 64 + l) * 16 + (c & 15)]);
                }
        pool[pp * 64 + c] = mv + bias[c];
    }
    __syncthreads();
    if (tid < 8) {
        float mx = -INFINITY;
        for (int c = 0; c < 64; ++c) mx = fmaxf(mx, pool[tid * 64 + c]);
        float s = 0.f;
        for (int c = 0; c < 64; ++c) s += __expf(pool[tid * 64 + c] - mx);
        float r = fmaxf(mx + logf(s), 0.f);
        const int pd = tid >> 2, ph = (tid >> 1) & 1, pw = tid & 1;
        const int dp = td * 2 + pd, hp = th * 2 + ph, wp = tw * 2 + pw;
        out[(((size_t)n * PD + dp) * PD + hp) * PD + wp] = r;
    }
}

extern "C" void kernel_launch(void* const* d_in, const int* in_sizes, int n_in,
                              void* d_out, int out_size, void* d_ws, size_t ws_size,
                              hipStream_t stream) {
    const float* x = (const float*)d_in[0];
    const float* w = (const float*)d_in[1];
    const float* b = (const float*)d_in[2];
    float* out = (float*)d_out;

    const size_t wg_bytes = (size_t)(27 * 64 * 32) * sizeof(unsigned short);  // 110592
    if (ws_size >= XB_BYTES + wg_bytes) {
        unsigned short* xbuf = (unsigned short*)d_ws;
        unsigned short* wgb  = (unsigned short*)((char*)d_ws + XB_BYTES);
        xpack_kernel<<<(16 * XP_POS + 255) / 256, 256, 0, stream>>>(x, xbuf);
        wpack_kernel<<<216, 256, 0, stream>>>(w, wgb);
        conv_mfma_kernel<<<16 * 6 * 12 * 3, 256, 0, stream>>>(xbuf, wgb, b, out);
    } else if (ws_size >= wg_bytes) {
        unsigned short* wgb = (unsigned short*)d_ws;
        wpack_kernel<<<216, 256, 0, stream>>>(w, wgb);
        conv_mfma_r3<<<16 * 12 * 12 * 3, 256, 0, stream>>>(x, wgb, b, out);
    } else {
        conv_fused_fallback<<<16 * 12 * 12 * 12, 256, 0, stream>>>(x, w, b, out);
    }
}